// Round 9
// baseline (912.360 us; speedup 1.0000x reference)
//
#include <hip/hip_runtime.h>

#define NS 1024   // spins / steps
#define NB 4096   // batch
#define NH 128    // hidden
#define HLF 512   // magnetization threshold (both up and down)

typedef __attribute__((ext_vector_type(8))) short short8;
typedef __attribute__((ext_vector_type(4))) float f32x4;
typedef __attribute__((ext_vector_type(4))) unsigned uint32x4;

__device__ __forceinline__ short f2bf(float x) {   // fp32 -> bf16 RNE
    unsigned u = __builtin_bit_cast(unsigned, x);
    u = (u + 0x7FFFu + ((u >> 16) & 1u)) >> 16;
    return (short)u;
}
__device__ __forceinline__ float vexp2(float x) {  // raw v_exp_f32 (2^x)
    float r;
    asm("v_exp_f32 %0, %1" : "=v"(r) : "v"(x));
    return r;
}

// Fully autonomous wave: one 64-lane wave owns 16 batch rows for all 1024
// steps. NO LDS, NO barriers. The MFMA D-layout (lane=batch col, regs=4
// hidden rows) is recycled directly as next step's B-operand (lane=batch col,
// regs=8 K-rows) by permuting W_hh's K-columns with the bit-swap
//   sigma(k): out[6:5]=k[6:5], out[4]=k[2], out[3:2]=k[4:3], out[1:0]=k[1:0]
// so that cvt_pk-packed D pairs of tiles (2kb, 2kb+1) ARE B-fragment kb.
__global__ __launch_bounds__(64, 1)
void pwf_kernel(const float* __restrict__ data_in,
                const float* __restrict__ W_ih,
                const float* __restrict__ W_hh,
                const float* __restrict__ b_ih,
                const float* __restrict__ b_hh,
                const float* __restrict__ W_lin,
                const float* __restrict__ b_lin,
                float* __restrict__ out)
{
    const int l  = threadIdx.x;     // lane 0..63
    const int g  = l >> 4;          // reg-group 0..3
    const int b  = l & 15;          // batch col (B/D) and A-row m
    const int b0 = blockIdx.x * 16;

    const float TL2E = 2.8853900817779268f;  // 2*log2(e): tanh in exp2 domain
    const float L2E  = 1.4426950408889634f;  // log2(e):   softmax in exp2 domain

    // ---- A fragments: sigma-permuted W_hh, registers forever (128 VGPRs) ----
    // afr[T][kb] lane (g, m=b), slot j: TL2E * W_hh[16T+m][sigma(32kb+8g+j)]
    // sigma cols for fixed g: 32kb + 4g + (j&3) + 16*(j>>2)  -> two float4 loads
    short8 afr[8][4];
    #pragma unroll
    for (int T = 0; T < 8; ++T) {
        const float* wr = W_hh + (size_t)(16 * T + b) * NH;
        #pragma unroll
        for (int kb = 0; kb < 4; ++kb) {
            const float* p = wr + 32 * kb + 4 * g;
            const float4 f0 = *(const float4*)(p);
            const float4 f1 = *(const float4*)(p + 16);
            short8 v;
            v[0] = f2bf(TL2E * f0.x); v[1] = f2bf(TL2E * f0.y);
            v[2] = f2bf(TL2E * f0.z); v[3] = f2bf(TL2E * f0.w);
            v[4] = f2bf(TL2E * f1.x); v[5] = f2bf(TL2E * f1.y);
            v[6] = f2bf(TL2E * f1.z); v[7] = f2bf(TL2E * f1.w);
            afr[T][kb] = v;
        }
    }
    // ---- per-lane constants: hidden i = 16T + 4g + r (96 VGPRs) ----
    float cv0[8][4], cv1[8][4], wdf[8][4];
    #pragma unroll
    for (int T = 0; T < 8; ++T) {
        #pragma unroll
        for (int r = 0; r < 4; ++r) {
            const int i = 16 * T + 4 * g + r;
            const float cb = b_ih[i] + b_hh[i];
            cv0[T][r] = TL2E * (W_ih[2 * i + 0] + cb);
            cv1[T][r] = TL2E * (W_ih[2 * i + 1] + cb);
            wdf[T][r] = L2E * (W_lin[NH + i] - W_lin[i]);   // logit-diff weights
        }
    }
    const float blD = L2E * (b_lin[1] - b_lin[0]);

    // ---- state ----
    short8 frag0 = {0,0,0,0,0,0,0,0}, frag1 = frag0, frag2 = frag0, frag3 = frag0;
    int   cntup = 0, cntdn = 0, sel = 0;      // sel=0: init input [1,0]
    int   eum = 0, edm = 0;                   // masks for pending out store
    float pdiff = 0.0f;                       // pending logit-diff (out[T-1])
    float suA = data_in[(size_t)(b0 + b) * 2];            // spin 0, channel 0
    float suB = data_in[((size_t)NB + b0 + b) * 2];       // spin 1

#define STEP(T, SU)                                                            \
    {                                                                          \
        if ((T) >= 1 && l < 16) {   /* store out[T-1] from prev step */        \
            const float ex = vexp2(pdiff);                                     \
            float p0 = __builtin_amdgcn_rcpf(1.0f + ex);                       \
            float p1 = 1.0f - p0;                                              \
            if (eum) { p0 = 0.0f; p1 = 1.0f; }                                 \
            if (edm) { p0 = 1.0f; p1 = 0.0f; }   /* down overrides up */       \
            *(float2*)&out[((size_t)((T) - 1) * NB + b0 + b) * 2] =            \
                make_float2(p0, p1);                                           \
        }                                                                      \
        const int umc = (cntup >= HLF);   /* M_T: cum spins[0..T-1] */         \
        const int dmc = (cntdn >= HLF);                                        \
        /* recurrence: 8 tiles x 4 MFMAs (serial acc per tile, 8-way ILP) */   \
        f32x4 acc[8];                                                          \
        _Pragma("unroll")                                                      \
        for (int T2 = 0; T2 < 8; ++T2) {                                       \
            f32x4 c = {0.f, 0.f, 0.f, 0.f};                                    \
            c = __builtin_amdgcn_mfma_f32_16x16x32_bf16(afr[T2][0], frag0, c, 0, 0, 0); \
            c = __builtin_amdgcn_mfma_f32_16x16x32_bf16(afr[T2][1], frag1, c, 0, 0, 0); \
            c = __builtin_amdgcn_mfma_f32_16x16x32_bf16(afr[T2][2], frag2, c, 0, 0, 0); \
            c = __builtin_amdgcn_mfma_f32_16x16x32_bf16(afr[T2][3], frag3, c, 0, 0, 0); \
            acc[T2] = c;                                                       \
        }                                                                      \
        /* tanh + logit-dot + bf16 pack */                                     \
        float ldp = 0.0f;                                                      \
        unsigned pka[8], pkb[8];                                               \
        _Pragma("unroll")                                                      \
        for (int T2 = 0; T2 < 8; ++T2) {                                       \
            float hn[4];                                                       \
            _Pragma("unroll")                                                  \
            for (int r = 0; r < 4; ++r) {                                      \
                const float cv = sel ? cv1[T2][r] : cv0[T2][r];                \
                const float e  = vexp2(acc[T2][r] + cv);                       \
                hn[r] = fmaf(__builtin_amdgcn_rcpf(e + 1.0f), -2.0f, 1.0f);    \
                ldp   = fmaf(wdf[T2][r], hn[r], ldp);                          \
            }                                                                  \
            asm("v_cvt_pk_bf16_f32 %0, %1, %2" : "=v"(pka[T2]) : "v"(hn[0]), "v"(hn[1])); \
            asm("v_cvt_pk_bf16_f32 %0, %1, %2" : "=v"(pkb[T2]) : "v"(hn[2]), "v"(hn[3])); \
        }                                                                      \
        ldp += __shfl_xor(ldp, 16);   /* reduce over g (4 lanes per batch) */  \
        ldp += __shfl_xor(ldp, 32);                                            \
        pdiff = ldp + blD;  eum = umc;  edm = dmc;   /* pend out[T] */         \
        /* rebuild B-fragments in-register (the sigma identity) */             \
        frag0 = __builtin_bit_cast(short8, (uint32x4){pka[0], pkb[0], pka[1], pkb[1]}); \
        frag1 = __builtin_bit_cast(short8, (uint32x4){pka[2], pkb[2], pka[3], pkb[3]}); \
        frag2 = __builtin_bit_cast(short8, (uint32x4){pka[4], pkb[4], pka[5], pkb[5]}); \
        frag3 = __builtin_bit_cast(short8, (uint32x4){pka[6], pkb[6], pka[7], pkb[7]}); \
        /* consume spin T, prefetch spin T+2 */                                \
        const int isup = ((SU) > 0.5f) ? 1 : 0;                                \
        cntup += isup;  cntdn += 1 - isup;  sel = 1 - isup;                    \
        const int tn = ((T) + 2 < NS) ? (T) + 2 : NS - 1;                      \
        (SU) = data_in[((size_t)tn * NB + b0 + b) * 2];                        \
    }

    for (int t = 0; t < NS; t += 2) {
        STEP(t, suA)
        STEP(t + 1, suB)
    }

    // ---- post-loop: out[NS-1] (pending from the last step) ----
    if (l < 16) {
        const float ex = vexp2(pdiff);
        float p0 = __builtin_amdgcn_rcpf(1.0f + ex);
        float p1 = 1.0f - p0;
        if (eum) { p0 = 0.0f; p1 = 1.0f; }
        if (edm) { p0 = 1.0f; p1 = 0.0f; }
        *(float2*)&out[((size_t)(NS - 1) * NB + b0 + b) * 2] = make_float2(p0, p1);
    }
}

extern "C" void kernel_launch(void* const* d_in, const int* in_sizes, int n_in,
                              void* d_out, int out_size, void* d_ws, size_t ws_size,
                              hipStream_t stream) {
    const float* data_in = (const float*)d_in[0];
    const float* W_ih    = (const float*)d_in[1];
    const float* W_hh    = (const float*)d_in[2];
    const float* b_ih    = (const float*)d_in[3];
    const float* b_hh    = (const float*)d_in[4];
    const float* W_lin   = (const float*)d_in[5];
    const float* b_lin   = (const float*)d_in[6];
    float* out = (float*)d_out;

    dim3 grid(NB / 16);   // 256 blocks = 256 autonomous waves, 1 per CU
    dim3 block(64);       // one wave
    pwf_kernel<<<grid, block, 0, stream>>>(data_in, W_ih, W_hh, b_ih, b_hh,
                                           W_lin, b_lin, out);
}

// Round 10
// 733.651 us; speedup vs baseline: 1.2436x; 1.2436x over previous
//
#include <hip/hip_runtime.h>

#define NS 1024   // spins / steps
#define NB 4096   // batch
#define NH 128    // hidden
#define HLF 512   // magnetization threshold
#define NT 512    // 8 waves

typedef __attribute__((ext_vector_type(8))) short short8;
typedef __attribute__((ext_vector_type(4))) float f32x4;

__device__ __forceinline__ short f2bf(float x) {   // fp32 -> bf16 RNE
    unsigned u = __builtin_bit_cast(unsigned, x);
    u = (u + 0x7FFFu + ((u >> 16) & 1u)) >> 16;
    return (short)u;
}
__device__ __forceinline__ float vexp2(float x) {  // raw v_exp_f32 (2^x)
    float r;
    asm("v_exp_f32 %0, %1" : "=v"(r) : "v"(x));
    return r;
}

// LDS-only barrier: drain lgkm, NOT vmcnt (spin prefetch + out stores fly on)
#define BARRIER() asm volatile("s_waitcnt lgkmcnt(0)\n\ts_barrier" ::: "memory")

#define MFMA __builtin_amdgcn_mfma_f32_16x16x32_bf16

// Two batch groups (A: rows b0..b0+15, B: b0+16..b0+31) software-pipelined
// through one 8-wave block. Phase A_t: read hA[t]->A-MFMAs, B-epilogue writes
// hB[t]. Phase B_t: read hB[t]->B-MFMAs, A-epilogue writes hA[t+1]. The
// epilogue (pure-VALU, reg inputs) of one group fills the ds_read+MFMA latency
// of the other. Single-buffered LDS per group (phase barrier covers anti-deps).
__global__ __launch_bounds__(NT, 1)
void pwf_kernel(const float* __restrict__ data_in,
                const float* __restrict__ W_ih,
                const float* __restrict__ W_hh,
                const float* __restrict__ b_ih,
                const float* __restrict__ b_hh,
                const float* __restrict__ W_lin,
                const float* __restrict__ b_lin,
                float* __restrict__ out)
{
    // rotated layout: elem(batch b, hid) at b*128 + ((hid + 8*b) & 127) [shorts]
    __shared__ __align__(16) short hlds[2][16 * NH];   // hA = [0], hB = [1]
    short* const hA = hlds[0];
    short* const hB = hlds[1];

    const int tid = threadIdx.x;
    const int w   = tid >> 6;       // wave 0..7 (hidden slice 16w..16w+15)
    const int l   = tid & 63;
    const int g   = l >> 4;         // k-group 0..3
    const int b   = l & 15;         // batch col within group / A-row m
    const int b0  = blockIdx.x * 32;

    const float TL2E = 2.8853900817779268f;  // 2*log2(e)
    const float L2E  = 1.4426950408889634f;  // log2(e)

    // ---- A fragments: W_hh rows (exp2-domain), registers forever ----
    const int hrow = w * 16 + b;
    short8 afrag[4];
    #pragma unroll
    for (int kb = 0; kb < 4; ++kb) {
        const float* src = W_hh + hrow * NH + kb * 32 + g * 8;
        short8 v;
        #pragma unroll
        for (int i = 0; i < 8; ++i) v[i] = f2bf(TL2E * src[i]);
        afrag[kb] = v;
    }
    // ---- logit A-fragment: row 0 = log2e*(W_lin[1]-W_lin[0]) ----
    short8 lfrag[4];
    #pragma unroll
    for (int kb = 0; kb < 4; ++kb) {
        short8 v;
        #pragma unroll
        for (int i = 0; i < 8; ++i) {
            const int k = kb * 32 + g * 8 + i;
            v[i] = (b == 0) ? f2bf(L2E * (W_lin[NH + k] - W_lin[k])) : (short)0;
        }
        lfrag[kb] = v;
    }
    // ---- per-C-reg input contributions: hid = w*16 + 4g + r ----
    float cv0[4], cv1[4];
    #pragma unroll
    for (int r = 0; r < 4; ++r) {
        const int hid = w * 16 + 4 * g + r;
        const float cb = b_ih[hid] + b_hh[hid];
        cv0[r] = TL2E * (W_ih[hid * 2 + 0] + cb);
        cv1[r] = TL2E * (W_ih[hid * 2 + 1] + cb);
    }
    const float blD = L2E * (b_lin[1] - b_lin[0]);

    // ---- LDS offsets (shorts) ----
    int aoff[4];
    #pragma unroll
    for (int kb = 0; kb < 4; ++kb)
        aoff[kb] = b * NH + ((kb * 32 + g * 8 + 8 * b) & 127);
    const int woffs = b * NH + ((w * 16 + 4 * g + 8 * b) & 127);

    // ---- init ----
    ((uint4*)hlds)[tid] = make_uint4(0u, 0u, 0u, 0u);   // 512*16B = hA+hB = 0
    f32x4 accA0 = {0,0,0,0}, accA1 = accA0, accB0 = accA0, accB1 = accA0;
    int selA = 0, cupA = 0, cdnA = 0, snapUA = 0, snapDA = 0;
    int selB = 0, cupB = 0, cdnB = 0, snapUB = 0, snapDB = 0;
    float edfA = 0.f, edfB = 0.f;
    int eumA = 0, edmA = 0, eumB = 0, edmB = 0;
    float sA0 = data_in[((size_t)0 * NB + b0 + b) * 2];
    float sA1 = data_in[((size_t)1 * NB + b0 + b) * 2];
    float sB0 = data_in[((size_t)0 * NB + b0 + 16 + b) * 2];
    float sB1 = data_in[((size_t)1 * NB + b0 + 16 + b) * 2];
    BARRIER();

    // ---- phase A_T: A reads hA[T], B-epilogue writes hB[T] (consumes spinB[T-1])
#define PHA(T, SBS)                                                            \
    {                                                                          \
        const short8 h0 = *(const short8*)&hA[aoff[0]];                        \
        const short8 h1 = *(const short8*)&hA[aoff[1]];                        \
        const short8 h2 = *(const short8*)&hA[aoff[2]];                        \
        const short8 h3 = *(const short8*)&hA[aoff[3]];                        \
        if (w == 0) {                                                          \
            if ((T) >= 2 && l < 16) {                                          \
                float p0 = __builtin_amdgcn_rcpf(1.0f + vexp2(edfA));          \
                float p1 = 1.0f - p0;                                          \
                if (eumA) { p0 = 0.0f; p1 = 1.0f; }                            \
                if (edmA) { p0 = 1.0f; p1 = 0.0f; }                            \
                *(float2*)&out[((size_t)((T) - 2) * NB + b0 + l) * 2] =        \
                    make_float2(p0, p1);                                       \
            }                                                                  \
            if ((T) >= 1) {                                                    \
                f32x4 zl = {0.f, 0.f, 0.f, 0.f};                               \
                f32x4 d01 = MFMA(lfrag[0], h0, zl, 0, 0, 0);                   \
                d01 = MFMA(lfrag[1], h1, d01, 0, 0, 0);                        \
                f32x4 d23 = MFMA(lfrag[2], h2, zl, 0, 0, 0);                   \
                d23 = MFMA(lfrag[3], h3, d23, 0, 0, 0);                        \
                edfA = d01[0] + d23[0] + blD;                                  \
                eumA = snapUA; edmA = snapDA;                                  \
            }                                                                  \
        }                                                                      \
        f32x4 zz = {0.f, 0.f, 0.f, 0.f};                                       \
        accA0 = MFMA(afrag[0], h0, zz, 0, 0, 0);                               \
        accA0 = MFMA(afrag[1], h1, accA0, 0, 0, 0);                            \
        accA1 = MFMA(afrag[2], h2, zz, 0, 0, 0);                               \
        accA1 = MFMA(afrag[3], h3, accA1, 0, 0, 0);                            \
        if ((T) >= 1) {   /* B-epilogue -> hB[T] */                            \
            snapUB = (cupB >= HLF); snapDB = (cdnB >= HLF);                    \
            float hn[4];                                                       \
            _Pragma("unroll")                                                  \
            for (int r = 0; r < 4; ++r) {                                      \
                const float cv = selB ? cv1[r] : cv0[r];                       \
                const float e  = vexp2(accB0[r] + accB1[r] + cv);              \
                hn[r] = fmaf(__builtin_amdgcn_rcpf(e + 1.0f), -2.0f, 1.0f);    \
            }                                                                  \
            unsigned pk01, pk23;                                               \
            asm("v_cvt_pk_bf16_f32 %0, %1, %2" : "=v"(pk01) : "v"(hn[0]), "v"(hn[1])); \
            asm("v_cvt_pk_bf16_f32 %0, %1, %2" : "=v"(pk23) : "v"(hn[2]), "v"(hn[3])); \
            *(uint2*)&hB[woffs] = make_uint2(pk01, pk23);                      \
            const int isup = ((SBS) > 0.5f) ? 1 : 0;   /* spinB[T-1] */        \
            cupB += isup; cdnB += 1 - isup; selB = 1 - isup;                   \
            const int tn = ((T) + 1 < NS) ? (T) + 1 : NS - 1;                  \
            (SBS) = data_in[((size_t)tn * NB + b0 + 16 + b) * 2];              \
        }                                                                      \
        BARRIER();                                                             \
    }

    // ---- phase B_T: B reads hB[T], A-epilogue writes hA[T+1] (consumes spinA[T])
#define PHB(T, SAS)                                                            \
    {                                                                          \
        const short8 h0 = *(const short8*)&hB[aoff[0]];                        \
        const short8 h1 = *(const short8*)&hB[aoff[1]];                        \
        const short8 h2 = *(const short8*)&hB[aoff[2]];                        \
        const short8 h3 = *(const short8*)&hB[aoff[3]];                        \
        if (w == 2) {                                                          \
            if ((T) >= 2 && l < 16) {                                          \
                float p0 = __builtin_amdgcn_rcpf(1.0f + vexp2(edfB));          \
                float p1 = 1.0f - p0;                                          \
                if (eumB) { p0 = 0.0f; p1 = 1.0f; }                            \
                if (edmB) { p0 = 1.0f; p1 = 0.0f; }                            \
                *(float2*)&out[((size_t)((T) - 2) * NB + b0 + 16 + l) * 2] =   \
                    make_float2(p0, p1);                                       \
            }                                                                  \
            if ((T) >= 1) {                                                    \
                f32x4 zl = {0.f, 0.f, 0.f, 0.f};                               \
                f32x4 d01 = MFMA(lfrag[0], h0, zl, 0, 0, 0);                   \
                d01 = MFMA(lfrag[1], h1, d01, 0, 0, 0);                        \
                f32x4 d23 = MFMA(lfrag[2], h2, zl, 0, 0, 0);                   \
                d23 = MFMA(lfrag[3], h3, d23, 0, 0, 0);                        \
                edfB = d01[0] + d23[0] + blD;                                  \
                eumB = snapUB; edmB = snapDB;                                  \
            }                                                                  \
        }                                                                      \
        f32x4 zz = {0.f, 0.f, 0.f, 0.f};                                       \
        accB0 = MFMA(afrag[0], h0, zz, 0, 0, 0);                               \
        accB0 = MFMA(afrag[1], h1, accB0, 0, 0, 0);                            \
        accB1 = MFMA(afrag[2], h2, zz, 0, 0, 0);                               \
        accB1 = MFMA(afrag[3], h3, accB1, 0, 0, 0);                            \
        {   /* A-epilogue -> hA[T+1] */                                        \
            snapUA = (cupA >= HLF); snapDA = (cdnA >= HLF);                    \
            float hn[4];                                                       \
            _Pragma("unroll")                                                  \
            for (int r = 0; r < 4; ++r) {                                      \
                const float cv = selA ? cv1[r] : cv0[r];                       \
                const float e  = vexp2(accA0[r] + accA1[r] + cv);              \
                hn[r] = fmaf(__builtin_amdgcn_rcpf(e + 1.0f), -2.0f, 1.0f);    \
            }                                                                  \
            unsigned pk01, pk23;                                               \
            asm("v_cvt_pk_bf16_f32 %0, %1, %2" : "=v"(pk01) : "v"(hn[0]), "v"(hn[1])); \
            asm("v_cvt_pk_bf16_f32 %0, %1, %2" : "=v"(pk23) : "v"(hn[2]), "v"(hn[3])); \
            *(uint2*)&hA[woffs] = make_uint2(pk01, pk23);                      \
            const int isup = ((SAS) > 0.5f) ? 1 : 0;   /* spinA[T] */          \
            cupA += isup; cdnA += 1 - isup; selA = 1 - isup;                   \
            const int tn = ((T) + 2 < NS) ? (T) + 2 : NS - 1;                  \
            (SAS) = data_in[((size_t)tn * NB + b0 + b) * 2];                   \
        }                                                                      \
        BARRIER();                                                             \
    }

    for (int t = 0; t < NS; t += 2) {
        PHA(t, sB1)        // consumes spinB[t-1] (odd slot; skipped at t=0)
        PHB(t, sA0)        // consumes spinA[t]   (even slot)
        PHA(t + 1, sB0)    // consumes spinB[t]   (even slot)
        PHB(t + 1, sA1)    // consumes spinA[t+1] (odd slot)
    }

    // ---- post-loop ----
    // B-final epilogue: write hB[NS] (input select = spinB[NS-2] = selB)
    {
        snapUB = (cupB >= HLF); snapDB = (cdnB >= HLF);
        float hn[4];
        #pragma unroll
        for (int r = 0; r < 4; ++r) {
            const float cv = selB ? cv1[r] : cv0[r];
            const float e  = vexp2(accB0[r] + accB1[r] + cv);
            hn[r] = fmaf(__builtin_amdgcn_rcpf(e + 1.0f), -2.0f, 1.0f);
        }
        unsigned pk01, pk23;
        asm("v_cvt_pk_bf16_f32 %0, %1, %2" : "=v"(pk01) : "v"(hn[0]), "v"(hn[1]));
        asm("v_cvt_pk_bf16_f32 %0, %1, %2" : "=v"(pk23) : "v"(hn[2]), "v"(hn[3]));
        *(uint2*)&hB[woffs] = make_uint2(pk01, pk23);
    }
    BARRIER();

    if (w == 0) {   // group A: flush out[NS-2], compute out[NS-1] from hA[NS]
        if (l < 16) {
            float p0 = __builtin_amdgcn_rcpf(1.0f + vexp2(edfA));
            float p1 = 1.0f - p0;
            if (eumA) { p0 = 0.0f; p1 = 1.0f; }
            if (edmA) { p0 = 1.0f; p1 = 0.0f; }
            *(float2*)&out[((size_t)(NS - 2) * NB + b0 + l) * 2] = make_float2(p0, p1);
        }
        const short8 h0 = *(const short8*)&hA[aoff[0]];
        const short8 h1 = *(const short8*)&hA[aoff[1]];
        const short8 h2 = *(const short8*)&hA[aoff[2]];
        const short8 h3 = *(const short8*)&hA[aoff[3]];
        f32x4 zl = {0.f, 0.f, 0.f, 0.f};
        f32x4 d01 = MFMA(lfrag[0], h0, zl, 0, 0, 0);
        d01 = MFMA(lfrag[1], h1, d01, 0, 0, 0);
        f32x4 d23 = MFMA(lfrag[2], h2, zl, 0, 0, 0);
        d23 = MFMA(lfrag[3], h3, d23, 0, 0, 0);
        const float fd = d01[0] + d23[0] + blD;
        if (l < 16) {
            float p0 = __builtin_amdgcn_rcpf(1.0f + vexp2(fd));
            float p1 = 1.0f - p0;
            if (snapUA) { p0 = 0.0f; p1 = 1.0f; }
            if (snapDA) { p0 = 1.0f; p1 = 0.0f; }
            *(float2*)&out[((size_t)(NS - 1) * NB + b0 + l) * 2] = make_float2(p0, p1);
        }
    }
    if (w == 2) {   // group B: flush out[NS-2], compute out[NS-1] from hB[NS]
        if (l < 16) {
            float p0 = __builtin_amdgcn_rcpf(1.0f + vexp2(edfB));
            float p1 = 1.0f - p0;
            if (eumB) { p0 = 0.0f; p1 = 1.0f; }
            if (edmB) { p0 = 1.0f; p1 = 0.0f; }
            *(float2*)&out[((size_t)(NS - 2) * NB + b0 + 16 + l) * 2] = make_float2(p0, p1);
        }
        const short8 h0 = *(const short8*)&hB[aoff[0]];
        const short8 h1 = *(const short8*)&hB[aoff[1]];
        const short8 h2 = *(const short8*)&hB[aoff[2]];
        const short8 h3 = *(const short8*)&hB[aoff[3]];
        f32x4 zl = {0.f, 0.f, 0.f, 0.f};
        f32x4 d01 = MFMA(lfrag[0], h0, zl, 0, 0, 0);
        d01 = MFMA(lfrag[1], h1, d01, 0, 0, 0);
        f32x4 d23 = MFMA(lfrag[2], h2, zl, 0, 0, 0);
        d23 = MFMA(lfrag[3], h3, d23, 0, 0, 0);
        const float fd = d01[0] + d23[0] + blD;
        if (l < 16) {
            float p0 = __builtin_amdgcn_rcpf(1.0f + vexp2(fd));
            float p1 = 1.0f - p0;
            if (snapUB) { p0 = 0.0f; p1 = 1.0f; }
            if (snapDB) { p0 = 1.0f; p1 = 0.0f; }
            *(float2*)&out[((size_t)(NS - 1) * NB + b0 + 16 + l) * 2] = make_float2(p0, p1);
        }
    }
}

extern "C" void kernel_launch(void* const* d_in, const int* in_sizes, int n_in,
                              void* d_out, int out_size, void* d_ws, size_t ws_size,
                              hipStream_t stream) {
    const float* data_in = (const float*)d_in[0];
    const float* W_ih    = (const float*)d_in[1];
    const float* W_hh    = (const float*)d_in[2];
    const float* b_ih    = (const float*)d_in[3];
    const float* b_hh    = (const float*)d_in[4];
    const float* W_lin   = (const float*)d_in[5];
    const float* b_lin   = (const float*)d_in[6];
    float* out = (float*)d_out;

    dim3 grid(NB / 32);   // 128 blocks, 2 pipelined batch groups each
    dim3 block(NT);       // 8 waves
    pwf_kernel<<<grid, block, 0, stream>>>(data_in, W_ih, W_hh, b_ih, b_hh,
                                           W_lin, b_lin, out);
}

// Round 11
// 551.137 us; speedup vs baseline: 1.6554x; 1.3312x over previous
//
#include <hip/hip_runtime.h>

#define NS 1024   // spins / steps
#define NB 4096   // batch
#define NH 128    // hidden
#define HLF 512   // magnetization threshold
#define NT 512    // 8 waves: 0-3 chain A, 4-7 chain B

typedef __attribute__((ext_vector_type(8))) short short8;
typedef __attribute__((ext_vector_type(4))) float f32x4;

__device__ __forceinline__ short f2bf(float x) {   // fp32 -> bf16 RNE
    unsigned u = __builtin_bit_cast(unsigned, x);
    u = (u + 0x7FFFu + ((u >> 16) & 1u)) >> 16;
    return (short)u;
}
__device__ __forceinline__ float vexp2(float x) {  // raw v_exp_f32 (2^x)
    float r;
    asm("v_exp_f32 %0, %1" : "=v"(r) : "v"(x));
    return r;
}

// LDS-only barrier: drain lgkm (h traffic), NOT vmcnt — spin prefetch and out
// stores stay in flight across steps.
#define BARRIER() asm volatile("s_waitcnt lgkmcnt(0)\n\ts_barrier" ::: "memory")
#define MFMA __builtin_amdgcn_mfma_f32_16x16x32_bf16

// Two independent 16-batch chains per block on DISJOINT waves (A: waves 0-3,
// B: waves 4-7) sharing one barrier. Each SIMD hosts one A-wave + one B-wave;
// their chains interleave (R8-style desync) with zero duplicated work.
// TRANSPOSED compute per chain (R7-proven): D = W_hh · h^T, A-operand = W_hh
// rows in registers forever; each wave owns 32 hidden rows (2 MFMA tiles).
// LDS: bf16 h per chain, rotated: elem(b, hid) at b*128 + ((hid+8b)&127).
__global__ __launch_bounds__(NT, 1)
void pwf_kernel(const float* __restrict__ data_in,
                const float* __restrict__ W_ih,
                const float* __restrict__ W_hh,
                const float* __restrict__ b_ih,
                const float* __restrict__ b_hh,
                const float* __restrict__ W_lin,
                const float* __restrict__ b_lin,
                float* __restrict__ out)
{
    __shared__ __align__(16) short hlds[2][2][16 * NH];   // [parity][chain], 16 KB

    const int tid = threadIdx.x;
    const int w   = tid >> 6;       // wave 0..7
    const int ch  = w >> 2;         // chain 0 (A) / 1 (B)
    const int wv  = w & 3;          // wave within chain: hidden 32*wv..32*wv+31
    const int l   = tid & 63;
    const int g   = l >> 4;         // k-group 0..3
    const int b   = l & 15;         // batch col within chain
    const int b0  = blockIdx.x * 32;
    const int ob  = b0 + ch * 16;           // chain's batch base
    const int bb  = ob + b;                 // this lane's batch row
    const int isLog = (w == 0) | (w == 7);  // logit waves (SIMD 0 and 3)

    const float TL2E = 2.8853900817779268f;  // 2*log2(e)
    const float L2E  = 1.4426950408889634f;  // log2(e)

    // ---- A fragments: W_hh rows (exp2-domain), registers forever ----
    const int hrX = wv * 32 + b;
    const int hrY = hrX + 16;
    short8 aX[4], aY[4];
    #pragma unroll
    for (int kb = 0; kb < 4; ++kb) {
        const float* sx = W_hh + hrX * NH + kb * 32 + g * 8;
        const float* sy = W_hh + hrY * NH + kb * 32 + g * 8;
        short8 vx, vy;
        #pragma unroll
        for (int i = 0; i < 8; ++i) { vx[i] = f2bf(TL2E * sx[i]); vy[i] = f2bf(TL2E * sy[i]); }
        aX[kb] = vx; aY[kb] = vy;
    }
    // ---- logit A-fragment: row 0 = log2e*(W_lin[1]-W_lin[0]) ----
    short8 lfrag[4];
    #pragma unroll
    for (int kb = 0; kb < 4; ++kb) {
        short8 v;
        #pragma unroll
        for (int i = 0; i < 8; ++i) {
            const int k = kb * 32 + g * 8 + i;
            v[i] = (b == 0) ? f2bf(L2E * (W_lin[NH + k] - W_lin[k])) : (short)0;
        }
        lfrag[kb] = v;
    }
    // ---- per-C-reg input contributions: hidX = wv*32+4g+r, hidY = +16 ----
    float cvX0[4], cvX1[4], cvY0[4], cvY1[4];
    #pragma unroll
    for (int r = 0; r < 4; ++r) {
        const int hx = wv * 32 + 4 * g + r;
        const int hy = hx + 16;
        const float cbx = b_ih[hx] + b_hh[hx];
        const float cby = b_ih[hy] + b_hh[hy];
        cvX0[r] = TL2E * (W_ih[hx * 2 + 0] + cbx);
        cvX1[r] = TL2E * (W_ih[hx * 2 + 1] + cbx);
        cvY0[r] = TL2E * (W_ih[hy * 2 + 0] + cby);
        cvY1[r] = TL2E * (W_ih[hy * 2 + 1] + cby);
    }
    const float blD = L2E * (b_lin[1] - b_lin[0]);

    // ---- LDS offsets (shorts), rotated layout ----
    int aoff[4];
    #pragma unroll
    for (int kb = 0; kb < 4; ++kb)
        aoff[kb] = b * NH + ((kb * 32 + g * 8 + 8 * b) & 127);
    const int woffX = b * NH + ((wv * 32 + 4 * g + 8 * b) & 127);
    const int woffY = b * NH + ((wv * 32 + 16 + 4 * g + 8 * b) & 127);

    // ---- init ----
    ((uint4*)hlds)[tid]      = make_uint4(0u, 0u, 0u, 0u);   // 16 KB zero
    ((uint4*)hlds)[tid + NT] = make_uint4(0u, 0u, 0u, 0u);
    int   cntup = 0, cntdn = 0, sel = 0;    // per-lane spin tracking (batch bb)
    int   ump = 0, dmp = 0;                 // mask snapshot (for out[T])
    int   eum = 0, edm = 0;                 // masks for pending out store
    float ediff = 0.0f;                     // pending logit-diff (out[T-2])
    float suA = data_in[((size_t)0 * NB + bb) * 2];
    float suB = data_in[((size_t)1 * NB + bb) * 2];
    BARRIER();

#define STEP(T, P, SU)                                                         \
    {                                                                          \
        const short* hr = hlds[P][ch];                                         \
        short* hw = hlds[(P) ^ 1][ch];                                         \
        const short8 h0 = *(const short8*)&hr[aoff[0]];                        \
        const short8 h1 = *(const short8*)&hr[aoff[1]];                        \
        const short8 h2 = *(const short8*)&hr[aoff[2]];                        \
        const short8 h3 = *(const short8*)&hr[aoff[3]];                        \
        if (isLog) {                                                           \
            if ((T) >= 2 && l < 16) {   /* deferred store out[T-2] */          \
                float p0 = __builtin_amdgcn_rcpf(1.0f + vexp2(ediff));         \
                float p1 = 1.0f - p0;                                          \
                if (eum) { p0 = 0.0f; p1 = 1.0f; }                             \
                if (edm) { p0 = 1.0f; p1 = 0.0f; }   /* down overrides */      \
                *(float2*)&out[((size_t)((T) - 2) * NB + ob + l) * 2] =        \
                    make_float2(p0, p1);                                       \
            }                                                                  \
            if ((T) >= 1) {             /* logit-diffs for out[T-1] */         \
                f32x4 zl = {0.f, 0.f, 0.f, 0.f};                               \
                f32x4 d01 = MFMA(lfrag[0], h0, zl, 0, 0, 0);                   \
                d01 = MFMA(lfrag[1], h1, d01, 0, 0, 0);                        \
                f32x4 d23 = MFMA(lfrag[2], h2, zl, 0, 0, 0);                   \
                d23 = MFMA(lfrag[3], h3, d23, 0, 0, 0);                        \
                ediff = d01[0] + d23[0] + blD;    /* valid on lanes l<16 */    \
                eum = ump; edm = dmp;             /* masks for out[T-1] */     \
            }                                                                  \
        }                                                                      \
        ump = (cntup >= HLF);   /* snapshot for out[T]: spins 0..T-1 */        \
        dmp = (cntdn >= HLF);                                                  \
        /* recurrence: two independent 4-deep MFMA chains (tiles X, Y) */      \
        f32x4 zz = {0.f, 0.f, 0.f, 0.f};                                       \
        f32x4 cX = MFMA(aX[0], h0, zz, 0, 0, 0);                               \
        cX = MFMA(aX[1], h1, cX, 0, 0, 0);                                     \
        cX = MFMA(aX[2], h2, cX, 0, 0, 0);                                     \
        cX = MFMA(aX[3], h3, cX, 0, 0, 0);                                     \
        f32x4 cY = MFMA(aY[0], h0, zz, 0, 0, 0);                               \
        cY = MFMA(aY[1], h1, cY, 0, 0, 0);                                     \
        cY = MFMA(aY[2], h2, cY, 0, 0, 0);                                     \
        cY = MFMA(aY[3], h3, cY, 0, 0, 0);                                     \
        float hnX[4], hnY[4];                                                  \
        _Pragma("unroll")                                                      \
        for (int r = 0; r < 4; ++r) {                                          \
            const float cvx = sel ? cvX1[r] : cvX0[r];                         \
            const float cvy = sel ? cvY1[r] : cvY0[r];                         \
            const float ex = vexp2(cX[r] + cvx);                               \
            const float ey = vexp2(cY[r] + cvy);                               \
            hnX[r] = fmaf(__builtin_amdgcn_rcpf(ex + 1.0f), -2.0f, 1.0f);      \
            hnY[r] = fmaf(__builtin_amdgcn_rcpf(ey + 1.0f), -2.0f, 1.0f);      \
        }                                                                      \
        unsigned pX01, pX23, pY01, pY23;                                       \
        asm("v_cvt_pk_bf16_f32 %0, %1, %2" : "=v"(pX01) : "v"(hnX[0]), "v"(hnX[1])); \
        asm("v_cvt_pk_bf16_f32 %0, %1, %2" : "=v"(pX23) : "v"(hnX[2]), "v"(hnX[3])); \
        asm("v_cvt_pk_bf16_f32 %0, %1, %2" : "=v"(pY01) : "v"(hnY[0]), "v"(hnY[1])); \
        asm("v_cvt_pk_bf16_f32 %0, %1, %2" : "=v"(pY23) : "v"(hnY[2]), "v"(hnY[3])); \
        *(uint2*)&hw[woffX] = make_uint2(pX01, pX23);                          \
        *(uint2*)&hw[woffY] = make_uint2(pY01, pY23);                          \
        {   /* consume spin T, prefetch spin T+2 (per-lane, batch bb) */       \
            const int isup = ((SU) > 0.5f) ? 1 : 0;                            \
            cntup += isup; cntdn += 1 - isup; sel = 1 - isup;                  \
            const int tn = ((T) + 2 < NS) ? (T) + 2 : NS - 1;                  \
            (SU) = data_in[((size_t)tn * NB + bb) * 2];                        \
        }                                                                      \
        BARRIER();                                                             \
    }

    for (int t = 0; t < NS; t += 2) {
        STEP(t, 0, suA)
        STEP(t + 1, 1, suB)
    }

    // ---- post-loop: flush out[NS-2]; out[NS-1] from h_NS (in parity 0) ----
    if (isLog) {
        if (l < 16) {
            float p0 = __builtin_amdgcn_rcpf(1.0f + vexp2(ediff));
            float p1 = 1.0f - p0;
            if (eum) { p0 = 0.0f; p1 = 1.0f; }
            if (edm) { p0 = 1.0f; p1 = 0.0f; }
            *(float2*)&out[((size_t)(NS - 2) * NB + ob + l) * 2] = make_float2(p0, p1);
        }
        const short* hr = hlds[0][ch];
        const short8 h0 = *(const short8*)&hr[aoff[0]];
        const short8 h1 = *(const short8*)&hr[aoff[1]];
        const short8 h2 = *(const short8*)&hr[aoff[2]];
        const short8 h3 = *(const short8*)&hr[aoff[3]];
        f32x4 zl = {0.f, 0.f, 0.f, 0.f};
        f32x4 d01 = MFMA(lfrag[0], h0, zl, 0, 0, 0);
        d01 = MFMA(lfrag[1], h1, d01, 0, 0, 0);
        f32x4 d23 = MFMA(lfrag[2], h2, zl, 0, 0, 0);
        d23 = MFMA(lfrag[3], h3, d23, 0, 0, 0);
        const float fd = d01[0] + d23[0] + blD;
        if (l < 16) {
            float p0 = __builtin_amdgcn_rcpf(1.0f + vexp2(fd));
            float p1 = 1.0f - p0;
            if (ump) { p0 = 0.0f; p1 = 1.0f; }      // masks: spins 0..NS-2
            if (dmp) { p0 = 1.0f; p1 = 0.0f; }
            *(float2*)&out[((size_t)(NS - 1) * NB + ob + l) * 2] = make_float2(p0, p1);
        }
    }
}

extern "C" void kernel_launch(void* const* d_in, const int* in_sizes, int n_in,
                              void* d_out, int out_size, void* d_ws, size_t ws_size,
                              hipStream_t stream) {
    const float* data_in = (const float*)d_in[0];
    const float* W_ih    = (const float*)d_in[1];
    const float* W_hh    = (const float*)d_in[2];
    const float* b_ih    = (const float*)d_in[3];
    const float* b_hh    = (const float*)d_in[4];
    const float* W_lin   = (const float*)d_in[5];
    const float* b_lin   = (const float*)d_in[6];
    float* out = (float*)d_out;

    dim3 grid(NB / 32);   // 128 blocks, each = 2 concurrent chains on disjoint waves
    dim3 block(NT);       // 8 waves
    pwf_kernel<<<grid, block, 0, stream>>>(data_in, W_ih, W_hh, b_ih, b_hh,
                                           W_lin, b_lin, out);
}

// Round 12
// 436.363 us; speedup vs baseline: 2.0908x; 1.2630x over previous
//
#include <hip/hip_runtime.h>

#define NS 1024   // spins / steps
#define NB 4096   // batch
#define NH 128    // hidden
#define HLF 512   // magnetization threshold
#define NT 512    // 8 waves, one 16-batch chain per block

typedef __attribute__((ext_vector_type(8))) short short8;
typedef __attribute__((ext_vector_type(4))) float f32x4;

__device__ __forceinline__ short f2bf(float x) {   // fp32 -> bf16 RNE
    unsigned u = __builtin_bit_cast(unsigned, x);
    u = (u + 0x7FFFu + ((u >> 16) & 1u)) >> 16;
    return (short)u;
}
__device__ __forceinline__ float vexp2(float x) {  // raw v_exp_f32 (2^x)
    float r;
    asm("v_exp_f32 %0, %1" : "=v"(r) : "v"(x));
    return r;
}

// LDS-only barrier: drain lgkm (h + lp traffic), NOT vmcnt — spin prefetch and
// out stores stay in flight across steps.
#define BARRIER() asm volatile("s_waitcnt lgkmcnt(0)\n\ts_barrier" ::: "memory")
#define MFMA __builtin_amdgcn_mfma_f32_16x16x32_bf16

// One 16-batch chain per block, 8 waves (1 hid-tile each, transposed compute:
// D = W_hh·h^T, A = W_hh rows in regs forever). Balanced logit path: waves 0-3
// each do ONE partial-logit MFMA (K-slice 32w) -> lp[parity][b][w]; the combine
// (sum+softmax+mask+store) rotates over waves 4-7 (static phase, x4 unroll).
// Per-lane spin/mask tracking; masks carried 2-deep in registers.
__global__ __launch_bounds__(NT, 1)
void pwf_kernel(const float* __restrict__ data_in,
                const float* __restrict__ W_ih,
                const float* __restrict__ W_hh,
                const float* __restrict__ b_ih,
                const float* __restrict__ b_hh,
                const float* __restrict__ W_lin,
                const float* __restrict__ b_lin,
                float* __restrict__ out)
{
    // rotated layout: elem(batch b, hid) at b*128 + ((hid + 8*b) & 127) [shorts]
    __shared__ __align__(16) short hlds[2][16 * NH];      // 8 KB, double-buffered
    __shared__ __align__(16) float lp[2][16][4];          // logit partials [P][b][w]

    const int tid = threadIdx.x;
    const int w   = tid >> 6;       // wave 0..7 (hidden slice 16w..16w+15)
    const int l   = tid & 63;
    const int g   = l >> 4;         // k-group 0..3
    const int b   = l & 15;         // batch col / A-row m
    const int b0  = blockIdx.x * 16;
    const int bb  = b0 + b;         // this lane's batch row
    const int ws  = w & 3;          // K-slice for partial-logit duty (waves 0-3)

    const float TL2E = 2.8853900817779268f;  // 2*log2(e)
    const float L2E  = 1.4426950408889634f;  // log2(e)

    // ---- A fragments: W_hh rows (exp2-domain), registers forever ----
    const int hrow = w * 16 + b;
    short8 af0, af1, af2, af3;
    {
        short8 t[4];
        #pragma unroll
        for (int kb = 0; kb < 4; ++kb) {
            const float* src = W_hh + hrow * NH + kb * 32 + g * 8;
            short8 v;
            #pragma unroll
            for (int i = 0; i < 8; ++i) v[i] = f2bf(TL2E * src[i]);
            t[kb] = v;
        }
        af0 = t[0]; af1 = t[1]; af2 = t[2]; af3 = t[3];
    }
    // ---- partial-logit A-fragment: row 0 = L2E*(W_lin[1]-W_lin[0]) on K-slice ws
    short8 lfrag;
    #pragma unroll
    for (int i = 0; i < 8; ++i) {
        const int k = 32 * ws + 8 * g + i;
        lfrag[i] = (b == 0) ? f2bf(L2E * (W_lin[NH + k] - W_lin[k])) : (short)0;
    }
    // ---- per-C-reg input contributions: hid = w*16 + 4g + r ----
    float cv0[4], cv1[4];
    #pragma unroll
    for (int r = 0; r < 4; ++r) {
        const int hid = w * 16 + 4 * g + r;
        const float cb = b_ih[hid] + b_hh[hid];
        cv0[r] = TL2E * (W_ih[hid * 2 + 0] + cb);
        cv1[r] = TL2E * (W_ih[hid * 2 + 1] + cb);
    }
    const float blD = L2E * (b_lin[1] - b_lin[0]);

    // ---- LDS offsets (shorts) ----
    int aoff[4];
    #pragma unroll
    for (int kb = 0; kb < 4; ++kb)
        aoff[kb] = b * NH + ((kb * 32 + g * 8 + 8 * b) & 127);
    const int aoffP = b * NH + ((32 * ws + 8 * g + 8 * b) & 127);  // partial B-frag
    const int woffs = b * NH + ((w * 16 + 4 * g + 8 * b) & 127);   // b64 h write

    // ---- init ----
    ((uint4*)hlds)[tid] = make_uint4(0u, 0u, 0u, 0u);   // 512*16B = both h buffers
    int   cntup = 0, cntdn = 0, sel = 0;   // per-lane spin tracking (batch bb)
    int   e1u = 0, e1d = 0, e2u = 0, e2d = 0;  // mask snapshots, 2-deep
    float s0 = data_in[((size_t)0 * NB + bb) * 2];
    float s1 = data_in[((size_t)1 * NB + bb) * 2];
    float s2 = data_in[((size_t)2 * NB + bb) * 2];
    float s3 = data_in[((size_t)3 * NB + bb) * 2];
    BARRIER();

#define STEP(T, P, PH, SU)                                                     \
    {                                                                          \
        const short* hr = hlds[P];                                             \
        short* hw = hlds[(P) ^ 1];                                             \
        const short8 h0 = *(const short8*)&hr[aoff[0]];                        \
        const short8 h1 = *(const short8*)&hr[aoff[1]];                        \
        const short8 h2 = *(const short8*)&hr[aoff[2]];                        \
        const short8 h3 = *(const short8*)&hr[aoff[3]];                        \
        if (w == 4 + (PH)) {   /* combine duty: store out[T-2] */              \
            if ((T) >= 2 && l < 16) {                                          \
                const float4 v = *(const float4*)&lp[(P) ^ 1][l][0];           \
                const float d = v.x + v.y + v.z + v.w + blD;                   \
                float p0 = __builtin_amdgcn_rcpf(1.0f + vexp2(d));             \
                float p1 = 1.0f - p0;                                          \
                if (e2u) { p0 = 0.0f; p1 = 1.0f; }                             \
                if (e2d) { p0 = 1.0f; p1 = 0.0f; }   /* down overrides */      \
                *(float2*)&out[((size_t)((T) - 2) * NB + b0 + l) * 2] =        \
                    make_float2(p0, p1);                                       \
            }                                                                  \
        }                                                                      \
        if (w < 4) {           /* partial-logit duty: K-slice 32w */           \
            const short8 hp = *(const short8*)&hr[aoffP];                      \
            f32x4 zl = {0.f, 0.f, 0.f, 0.f};                                   \
            const f32x4 cl = MFMA(lfrag, hp, zl, 0, 0, 0);                     \
            if (l < 16) lp[P][l][ws] = cl[0];                                  \
        }                                                                      \
        /* recurrence: two independent 2-deep MFMA chains */                   \
        f32x4 zz = {0.f, 0.f, 0.f, 0.f};                                       \
        f32x4 c01 = MFMA(af0, h0, zz, 0, 0, 0);                                \
        c01 = MFMA(af1, h1, c01, 0, 0, 0);                                     \
        f32x4 c23 = MFMA(af2, h2, zz, 0, 0, 0);                                \
        c23 = MFMA(af3, h3, c23, 0, 0, 0);                                     \
        e2u = e1u; e2d = e1d;               /* shift mask pipeline */          \
        e1u = (cntup >= HLF); e1d = (cntdn >= HLF);   /* snap(T) */            \
        float hn[4];                                                           \
        _Pragma("unroll")                                                      \
        for (int r = 0; r < 4; ++r) {                                          \
            const float cv = sel ? cv1[r] : cv0[r];                            \
            const float e  = vexp2(c01[r] + c23[r] + cv);                      \
            hn[r] = fmaf(__builtin_amdgcn_rcpf(e + 1.0f), -2.0f, 1.0f);        \
        }                                                                      \
        unsigned pk01, pk23;                                                   \
        asm("v_cvt_pk_bf16_f32 %0, %1, %2" : "=v"(pk01) : "v"(hn[0]), "v"(hn[1])); \
        asm("v_cvt_pk_bf16_f32 %0, %1, %2" : "=v"(pk23) : "v"(hn[2]), "v"(hn[3])); \
        *(uint2*)&hw[woffs] = make_uint2(pk01, pk23);                          \
        {   /* consume spin T, prefetch spin T+4 */                            \
            const int isup = ((SU) > 0.5f) ? 1 : 0;                            \
            cntup += isup; cntdn += 1 - isup; sel = 1 - isup;                  \
            const int tn = ((T) + 4 < NS) ? (T) + 4 : NS - 1;                  \
            (SU) = data_in[((size_t)tn * NB + bb) * 2];                        \
        }                                                                      \
        BARRIER();                                                             \
    }

    for (int t = 0; t < NS; t += 4) {
        STEP(t,     0, 0, s0)
        STEP(t + 1, 1, 1, s1)
        STEP(t + 2, 0, 2, s2)
        STEP(t + 3, 1, 3, s3)
    }

    // ---- post-loop ----
    // waves 0-3: partial logit on h[NS] (buffer parity 0) -> lp[0]
    if (w < 4) {
        const short8 hp = *(const short8*)&hlds[0][aoffP];
        f32x4 zl = {0.f, 0.f, 0.f, 0.f};
        const f32x4 cl = MFMA(lfrag, hp, zl, 0, 0, 0);
        if (l < 16) lp[0][l][ws] = cl[0];
    }
    BARRIER();
    if (w == 4 && l < 16) {
        // out[NS-2] from lp[1] (partials of step NS-1), mask = snap(NS-2) = e2
        {
            const float4 v = *(const float4*)&lp[1][l][0];
            const float d = v.x + v.y + v.z + v.w + blD;
            float p0 = __builtin_amdgcn_rcpf(1.0f + vexp2(d));
            float p1 = 1.0f - p0;
            if (e2u) { p0 = 0.0f; p1 = 1.0f; }
            if (e2d) { p0 = 1.0f; p1 = 0.0f; }
            *(float2*)&out[((size_t)(NS - 2) * NB + b0 + l) * 2] = make_float2(p0, p1);
        }
        // out[NS-1] from lp[0] (partials of h[NS]), mask = snap(NS-1) = e1
        {
            const float4 v = *(const float4*)&lp[0][l][0];
            const float d = v.x + v.y + v.z + v.w + blD;
            float p0 = __builtin_amdgcn_rcpf(1.0f + vexp2(d));
            float p1 = 1.0f - p0;
            if (e1u) { p0 = 0.0f; p1 = 1.0f; }
            if (e1d) { p0 = 1.0f; p1 = 0.0f; }
            *(float2*)&out[((size_t)(NS - 1) * NB + b0 + l) * 2] = make_float2(p0, p1);
        }
    }
}

extern "C" void kernel_launch(void* const* d_in, const int* in_sizes, int n_in,
                              void* d_out, int out_size, void* d_ws, size_t ws_size,
                              hipStream_t stream) {
    const float* data_in = (const float*)d_in[0];
    const float* W_ih    = (const float*)d_in[1];
    const float* W_hh    = (const float*)d_in[2];
    const float* b_ih    = (const float*)d_in[3];
    const float* b_hh    = (const float*)d_in[4];
    const float* W_lin   = (const float*)d_in[5];
    const float* b_lin   = (const float*)d_in[6];
    float* out = (float*)d_out;

    dim3 grid(NB / 16);   // 256 blocks, one 16-batch chain per CU
    dim3 block(NT);       // 8 waves (2 per SIMD)
    pwf_kernel<<<grid, block, 0, stream>>>(data_in, W_ih, W_hh, b_ih, b_hh,
                                           W_lin, b_lin, out);
}